// Round 1
// baseline (203.375 us; speedup 1.0000x reference)
//
#include <hip/hip_runtime.h>
#include <stdint.h>

#define BB 2
#define NN 2048
#define EE 768
#define HH 12
#define DD 64
#define GG 16

typedef unsigned short u16;
typedef unsigned int u32;
typedef __attribute__((ext_vector_type(8))) short short8;
typedef __attribute__((ext_vector_type(4))) float f32x4;
typedef __attribute__((ext_vector_type(4))) unsigned short u16x4;

__device__ __forceinline__ u16 f2bf(float f) {
  union { float f; u32 u; } a; a.f = f;
  u32 r = a.u + 0x7FFFu + ((a.u >> 16) & 1u);
  return (u16)(r >> 16);
}

__device__ __forceinline__ float silu_f(float v) { return v / (1.f + __expf(-v)); }

__device__ __forceinline__ void gload16(const u16* g, char* l) {
  __builtin_amdgcn_global_load_lds(
      (const __attribute__((address_space(1))) void*)(g),
      (__attribute__((address_space(3))) void*)(l), 16, 0, 0);
}

// Stage a ROWS x 64 bf16 tile (row-major source, leading dim ld) into LDS.
// 16B chunks, XOR-swizzled within each row so fragment reads are ~conflict-free.
// LDS chunk c holds elements [row=c/8][k = ((c&7)^(row&7))*8 .. +8).
template<int ROWS>
__device__ __forceinline__ void stage_tile(const u16* __restrict__ gb, int ld, int row0, int col0,
                                           char* lds, int tid) {
  int wid = tid >> 6;
#pragma unroll
  for (int it = 0; it < ROWS / 32; ++it) {
    int c = it * 256 + tid;
    int r = c >> 3;
    int g = (c & 7) ^ (r & 7);
    gload16(gb + (size_t)(row0 + r) * ld + col0 + g * 8,
            lds + (it * 256 + wid * 64) * 16);  // wave-uniform base; HW adds lane*16
  }
}

// Read an 8-bf16 fragment: tile row `row`, k-group gk (8 elems), undoing the XOR swizzle.
__device__ __forceinline__ short8 read_frag(const char* lds, int row, int gk) {
  return *(const short8*)(lds + (((row << 3) | (gk ^ (row & 7))) << 4));
}

// ---------------- x -> bf16 ----------------
__global__ __launch_bounds__(256) void xconv_kernel(const float* __restrict__ x, u16* __restrict__ xb) {
  int i = blockIdx.x * 256 + threadIdx.x;
  float4 v = ((const float4*)x)[i];
  u16x4 o;
  o.x = f2bf(v.x); o.y = f2bf(v.y); o.z = f2bf(v.z); o.w = f2bf(v.w);
  ((u16x4*)xb)[i] = o;
}

// ---------------- W (768x768 f32) -> W^T bf16 ----------------
__global__ __launch_bounds__(256) void wconv_kernel(const float* __restrict__ Wq, const float* __restrict__ Wk,
    const float* __restrict__ Wv, const float* __restrict__ Wo,
    u16* __restrict__ Wqt, u16* __restrict__ Wkt, u16* __restrict__ Wvt, u16* __restrict__ Wot) {
  const float* src; u16* dst;
  int z = blockIdx.z;
  if (z == 0)      { src = Wq; dst = Wqt; }
  else if (z == 1) { src = Wk; dst = Wkt; }
  else if (z == 2) { src = Wv; dst = Wvt; }
  else             { src = Wo; dst = Wot; }
  __shared__ float tb[64][65];
  int k0 = blockIdx.x * 64, n0 = blockIdx.y * 64;
  int tid = threadIdx.x;
#pragma unroll
  for (int i = 0; i < 16; ++i) {
    int idx = i * 256 + tid;
    int r = idx >> 6, c = idx & 63;
    tb[r][c] = src[(size_t)(k0 + r) * EE + n0 + c];
  }
  __syncthreads();
#pragma unroll
  for (int i = 0; i < 16; ++i) {
    int idx = i * 256 + tid;
    int rn = idx >> 6, ck = idx & 63;
    dst[(size_t)(n0 + rn) * EE + k0 + ck] = f2bf(tb[ck][rn]);  // dst[n][k] = src[k][n]
  }
}

// ---------------- t = x @ Wg1 (fp32, exact gate path) ----------------
__global__ __launch_bounds__(256) void tg_kernel(const float* __restrict__ x, const float* __restrict__ Wg1,
                                                 float* __restrict__ tg) {
  int tid = threadIdx.x, lane = tid & 63, wid = tid >> 6;
  int m = blockIdx.x * 4 + wid;
  int col = lane & 15, sl = lane >> 4;
  const float* xr = x + (size_t)m * EE + sl * 192;
  float acc = 0.f;
#pragma unroll 4
  for (int i = 0; i < 48; ++i) {
    float4 xv = ((const float4*)xr)[i];
    int kk = sl * 192 + i * 4;
    acc += xv.x * Wg1[(kk + 0) * GG + col];
    acc += xv.y * Wg1[(kk + 1) * GG + col];
    acc += xv.z * Wg1[(kk + 2) * GG + col];
    acc += xv.w * Wg1[(kk + 3) * GG + col];
  }
  acc += __shfl_down(acc, 32);
  acc += __shfl_down(acc, 16);
  if (lane < 16) tg[(size_t)m * GG + col] = acc;
}

// ---------------- QKV projection: silu(x@W), q/k in [b,h,n,d], v transposed [b,h,d,n] ----------------
__global__ __launch_bounds__(256) void qkv_gemm(const u16* __restrict__ xb,
    const u16* __restrict__ Wqt, const u16* __restrict__ Wkt, const u16* __restrict__ Wvt,
    u16* __restrict__ qp, u16* __restrict__ kp, u16* __restrict__ vtp) {
  __shared__ __attribute__((aligned(16))) char As[16384];
  __shared__ __attribute__((aligned(16))) char Zs[16384];
  int tid = threadIdx.x, lane = tid & 63, wid = tid >> 6;
  int m0 = blockIdx.x * 128, n0 = blockIdx.y * 128, w = blockIdx.z;
  const u16* Zt = (w == 0) ? Wqt : (w == 1) ? Wkt : Wvt;
  int wm = wid >> 1, wn = wid & 1;
  f32x4 acc[4][4] = {};
  for (int kt = 0; kt < EE / 64; ++kt) {
    __syncthreads();
    stage_tile<128>(xb, EE, m0, kt * 64, As, tid);
    stage_tile<128>(Zt, EE, n0, kt * 64, Zs, tid);
    __syncthreads();
    short8 af[2][4], bfr[2][4];
#pragma unroll
    for (int ds = 0; ds < 2; ++ds) {
      int gk = ds * 4 + (lane >> 4);
#pragma unroll
      for (int i = 0; i < 4; ++i) {
        af[ds][i]  = read_frag(As, wm * 64 + i * 16 + (lane & 15), gk);
        bfr[ds][i] = read_frag(Zs, wn * 64 + i * 16 + (lane & 15), gk);
      }
    }
#pragma unroll
    for (int mi = 0; mi < 4; ++mi)
#pragma unroll
      for (int ni = 0; ni < 4; ++ni) {
        acc[mi][ni] = __builtin_amdgcn_mfma_f32_16x16x32_bf16(af[0][mi], bfr[0][ni], acc[mi][ni], 0, 0, 0);
        acc[mi][ni] = __builtin_amdgcn_mfma_f32_16x16x32_bf16(af[1][mi], bfr[1][ni], acc[mi][ni], 0, 0, 0);
      }
  }
#pragma unroll
  for (int mi = 0; mi < 4; ++mi) {
    int mbase = m0 + wm * 64 + mi * 16 + ((lane >> 4) << 2);
    int bidx = mbase >> 11, nbase = mbase & 2047;
#pragma unroll
    for (int ni = 0; ni < 4; ++ni) {
      int e = n0 + wn * 64 + ni * 16 + (lane & 15);
      int h = e >> 6, d = e & 63;
      if (w < 2) {
        u16* dst = (w == 0 ? qp : kp) + (size_t)(bidx * HH + h) * NN * DD + d;
#pragma unroll
        for (int r = 0; r < 4; ++r)
          dst[(size_t)(nbase + r) * DD] = f2bf(silu_f(acc[mi][ni][r]));
      } else {
        u16x4 pk;
        pk.x = f2bf(silu_f(acc[mi][ni][0]));
        pk.y = f2bf(silu_f(acc[mi][ni][1]));
        pk.z = f2bf(silu_f(acc[mi][ni][2]));
        pk.w = f2bf(silu_f(acc[mi][ni][3]));
        *(u16x4*)(vtp + (size_t)((bidx * HH + h) * DD + d) * NN + nbase) = pk;
      }
    }
  }
}

// ---------------- decay attention: O = (QK^T . decay) V, per (b,h), 64-query tiles ----------------
__global__ __launch_bounds__(256) void attn_kernel(const u16* __restrict__ qp, const u16* __restrict__ kp,
    const u16* __restrict__ vtp, const float* __restrict__ slopes, float* __restrict__ attn) {
  __shared__ __attribute__((aligned(16))) char Ks[8192];
  __shared__ __attribute__((aligned(16))) char Vs[8192];
  __shared__ __attribute__((aligned(16))) char Ps[4][2304];  // per-wave P, 16 rows x 144B stride
  int tid = threadIdx.x, lane = tid & 63, wid = tid >> 6;
  int q0 = blockIdx.x * 64;
  int bh = blockIdx.y, b = bh / HH, h = bh % HH;
  float slope = slopes[h];  // negative
  const u16* qbh = qp + (size_t)bh * NN * DD;
  const u16* kbh = kp + (size_t)bh * NN * DD;
  const u16* vbh = vtp + (size_t)bh * DD * NN;

  // Q fragments live in registers for the whole kernel (wave owns 16 q-rows)
  int qrow = q0 + wid * 16 + (lane & 15);
  short8 qf0 = *(const short8*)(qbh + (size_t)qrow * DD + ((lane >> 4) << 3));
  short8 qf1 = *(const short8*)(qbh + (size_t)qrow * DD + 32 + ((lane >> 4) << 3));

  f32x4 oacc[4] = {};
  // skip key tiles whose max decay < e^-30 (reference fp32 underflows to 0 far before that)
  float window = 30.f / (-slope);
  float jminf = (float)q0 - window;
  int kt_min = (jminf <= 0.f) ? 0 : (((int)jminf) >> 6);
  int kt_max = q0 >> 6;
  char* Pw = Ps[wid];

  for (int kt = kt_min; kt <= kt_max; ++kt) {
    __syncthreads();
    stage_tile<64>(kbh, DD, kt * 64, 0, Ks, tid);   // K tile: 64 keys x 64 d
    stage_tile<64>(vbh, NN, 0, kt * 64, Vs, tid);   // V^T tile: 64 d x 64 keys
    __syncthreads();
#pragma unroll
    for (int jt = 0; jt < 4; ++jt) {
      f32x4 s = {};
      s = __builtin_amdgcn_mfma_f32_16x16x32_bf16(qf0, read_frag(Ks, jt * 16 + (lane & 15), (lane >> 4)), s, 0, 0, 0);
      s = __builtin_amdgcn_mfma_f32_16x16x32_bf16(qf1, read_frag(Ks, jt * 16 + (lane & 15), 4 + (lane >> 4)), s, 0, 0, 0);
      int jg = kt * 64 + jt * 16 + (lane & 15);
#pragma unroll
      for (int r = 0; r < 4; ++r) {
        int qi = q0 + wid * 16 + ((lane >> 4) << 2) + r;
        int diff = qi - jg;
        float val = (diff >= 0) ? s[r] * __expf(slope * (float)diff) : 0.f;
        // C-layout -> A-layout transform via wave-private LDS
        *(u16*)(Pw + ((((lane >> 4) << 2) + r) * 72 + jt * 16 + (lane & 15)) * 2) = f2bf(val);
      }
    }
    __syncthreads();  // safety: P write->read ordering (wave-private, but pin the compiler)
#pragma unroll
    for (int ks = 0; ks < 2; ++ks) {
      short8 pf = *(const short8*)(Pw + (lane & 15) * 144 + ks * 64 + ((lane >> 4) << 4));
#pragma unroll
      for (int dt = 0; dt < 4; ++dt) {
        oacc[dt] = __builtin_amdgcn_mfma_f32_16x16x32_bf16(
            pf, read_frag(Vs, dt * 16 + (lane & 15), ks * 4 + (lane >> 4)), oacc[dt], 0, 0, 0);
      }
    }
  }
#pragma unroll
  for (int dt = 0; dt < 4; ++dt) {
#pragma unroll
    for (int r = 0; r < 4; ++r) {
      int qi = q0 + wid * 16 + ((lane >> 4) << 2) + r;
      int e = h * 64 + dt * 16 + (lane & 15);
      attn[(size_t)(b * NN + qi) * EE + e] = oacc[dt][r];
    }
  }
}

// ---------------- gate: gated = bf16(attn * sigmoid(t @ Wg2)) ----------------
__global__ __launch_bounds__(256) void gate_kernel(const float* __restrict__ attn, const float* __restrict__ tg,
    const float* __restrict__ Wg2, u16* __restrict__ gated) {
  int m0 = blockIdx.x * 8;
  __shared__ float ts[8][16];
  int tid = threadIdx.x;
  if (tid < 128) ts[tid >> 4][tid & 15] = tg[(size_t)(m0 + (tid >> 4)) * GG + (tid & 15)];
  __syncthreads();
  for (int e = tid; e < EE; e += 256) {
    float wv[16];
#pragma unroll
    for (int g = 0; g < 16; ++g) wv[g] = Wg2[g * EE + e];
#pragma unroll
    for (int r = 0; r < 8; ++r) {
      float gg = 0.f;
#pragma unroll
      for (int g = 0; g < 16; ++g) gg += ts[r][g] * wv[g];
      float sg = 1.f / (1.f + __expf(-gg));
      gated[(size_t)(m0 + r) * EE + e] = f2bf(attn[(size_t)(m0 + r) * EE + e] * sg);
    }
  }
}

// ---------------- y = gated @ Wo (fp32 out) ----------------
__global__ __launch_bounds__(256) void wo_gemm(const u16* __restrict__ A, const u16* __restrict__ Zt,
                                               float* __restrict__ Y) {
  __shared__ __attribute__((aligned(16))) char As[16384];
  __shared__ __attribute__((aligned(16))) char Zs[16384];
  int tid = threadIdx.x, lane = tid & 63, wid = tid >> 6;
  int m0 = blockIdx.x * 128, n0 = blockIdx.y * 128;
  int wm = wid >> 1, wn = wid & 1;
  f32x4 acc[4][4] = {};
  for (int kt = 0; kt < EE / 64; ++kt) {
    __syncthreads();
    stage_tile<128>(A, EE, m0, kt * 64, As, tid);
    stage_tile<128>(Zt, EE, n0, kt * 64, Zs, tid);
    __syncthreads();
    short8 af[2][4], bfr[2][4];
#pragma unroll
    for (int ds = 0; ds < 2; ++ds) {
      int gk = ds * 4 + (lane >> 4);
#pragma unroll
      for (int i = 0; i < 4; ++i) {
        af[ds][i]  = read_frag(As, wm * 64 + i * 16 + (lane & 15), gk);
        bfr[ds][i] = read_frag(Zs, wn * 64 + i * 16 + (lane & 15), gk);
      }
    }
#pragma unroll
    for (int mi = 0; mi < 4; ++mi)
#pragma unroll
      for (int ni = 0; ni < 4; ++ni) {
        acc[mi][ni] = __builtin_amdgcn_mfma_f32_16x16x32_bf16(af[0][mi], bfr[0][ni], acc[mi][ni], 0, 0, 0);
        acc[mi][ni] = __builtin_amdgcn_mfma_f32_16x16x32_bf16(af[1][mi], bfr[1][ni], acc[mi][ni], 0, 0, 0);
      }
  }
#pragma unroll
  for (int mi = 0; mi < 4; ++mi) {
    int mbase = m0 + wm * 64 + mi * 16 + ((lane >> 4) << 2);
#pragma unroll
    for (int ni = 0; ni < 4; ++ni) {
      int e = n0 + wn * 64 + ni * 16 + (lane & 15);
#pragma unroll
      for (int r = 0; r < 4; ++r)
        Y[(size_t)(mbase + r) * EE + e] = acc[mi][ni][r];
    }
  }
}

// ---------------- layernorm over E=768, one block per row ----------------
__global__ __launch_bounds__(256) void ln_kernel(const float* __restrict__ y, const float* __restrict__ w,
    const float* __restrict__ bb, float* __restrict__ out) {
  int m = blockIdx.x, tid = threadIdx.x;
  const float* yr = y + (size_t)m * EE;
  float v0 = yr[tid], v1 = yr[tid + 256], v2 = yr[tid + 512];
  float s = v0 + v1 + v2;
  float s2 = v0 * v0 + v1 * v1 + v2 * v2;
#pragma unroll
  for (int off = 32; off > 0; off >>= 1) {
    s += __shfl_down(s, off);
    s2 += __shfl_down(s2, off);
  }
  __shared__ float ss[4], ssq[4];
  int lane = tid & 63, wid = tid >> 6;
  if (lane == 0) { ss[wid] = s; ssq[wid] = s2; }
  __syncthreads();
  s = ss[0] + ss[1] + ss[2] + ss[3];
  s2 = ssq[0] + ssq[1] + ssq[2] + ssq[3];
  float mu = s * (1.f / 768.f);
  float var = s2 * (1.f / 768.f) - mu * mu;
  float rs = rsqrtf(var + 1e-5f);
  float* orow = out + (size_t)m * EE;
  orow[tid]       = (v0 - mu) * rs * w[tid]       + bb[tid];
  orow[tid + 256] = (v1 - mu) * rs * w[tid + 256] + bb[tid + 256];
  orow[tid + 512] = (v2 - mu) * rs * w[tid + 512] + bb[tid + 512];
}

extern "C" void kernel_launch(void* const* d_in, const int* in_sizes, int n_in,
                              void* d_out, int out_size, void* d_ws, size_t ws_size,
                              hipStream_t stream) {
  (void)in_sizes; (void)n_in; (void)out_size; (void)ws_size;
  const float* x   = (const float*)d_in[0];
  const float* ls  = (const float*)d_in[1];
  const float* Wq  = (const float*)d_in[2];
  const float* Wk  = (const float*)d_in[3];
  const float* Wv  = (const float*)d_in[4];
  const float* Wo  = (const float*)d_in[5];
  const float* Wg1 = (const float*)d_in[6];
  const float* Wg2 = (const float*)d_in[7];
  const float* lnw = (const float*)d_in[8];
  const float* lnb = (const float*)d_in[9];

  char* p = (char*)d_ws;
  u16* xb   = (u16*)(p + 0);          // 6291456 B  (reused as `gated` after QKV GEMM)
  u16* Wqt  = (u16*)(p + 6291456);    // 1179648 B
  u16* Wkt  = (u16*)(p + 7471104);
  u16* Wvt  = (u16*)(p + 8650752);
  u16* Wot  = (u16*)(p + 9830400);
  u16* qq   = (u16*)(p + 11010048);   // 6291456 B (reused as `yy` after attention)
  u16* kk   = (u16*)(p + 17301504);   // 6291456 B
  u16* vt   = (u16*)(p + 23592960);   // 6291456 B
  float* tg = (float*)(p + 29884416); // 262144 B
  float* at = (float*)(p + 30146560); // 12582912 B  (end: 42729472)
  u16* gated = xb;
  float* yy = (float*)(p + 11010048);
  float* out = (float*)d_out;

  hipLaunchKernelGGL(xconv_kernel, dim3(3072), dim3(256), 0, stream, x, xb);
  hipLaunchKernelGGL(wconv_kernel, dim3(12, 12, 4), dim3(256), 0, stream, Wq, Wk, Wv, Wo, Wqt, Wkt, Wvt, Wot);
  hipLaunchKernelGGL(tg_kernel, dim3(1024), dim3(256), 0, stream, x, Wg1, tg);
  hipLaunchKernelGGL(qkv_gemm, dim3(32, 6, 3), dim3(256), 0, stream, xb, Wqt, Wkt, Wvt, qq, kk, vt);
  hipLaunchKernelGGL(attn_kernel, dim3(32, 24), dim3(256), 0, stream, qq, kk, vt, ls, at);
  hipLaunchKernelGGL(gate_kernel, dim3(512), dim3(256), 0, stream, at, tg, Wg2, gated);
  hipLaunchKernelGGL(wo_gemm, dim3(32, 6), dim3(256), 0, stream, gated, Wot, yy);
  hipLaunchKernelGGL(ln_kernel, dim3(4096), dim3(256), 0, stream, yy, lnw, lnb, out);
}